// Round 16
// baseline (67.597 us; speedup 1.0000x reference)
//
#include <hip/hip_runtime.h>
#include <stdint.h>

// Fused 3-level B3-spline UWT, fp32 in/out. x:(16,1024,1024)->out:(16,4,1024,1024).
// R15 pk-f16 kernel + 2-tile async pipeline (T14): each block does two
// horizontally-adjacent 64x64 tiles; tile B's stage loads are issued into
// registers right after tile A's stage barrier and consumed after A's passB,
// hiding B's stage latency under A's compute and overlapping A's store drain
// with B's compute. 36.5 KB LDS, TB=256, 2048 blocks.

typedef float     f4v __attribute__((ext_vector_type(4)));
typedef _Float16  h2v __attribute__((ext_vector_type(2)));

constexpr int TB  = 256;
constexpr int VH  = 14;     // vertical halo (2+4+8)
constexpr int XR  = 92;     // xs rows
constexpr int XCP = 93;     // xs column pitch (uint2 slots), odd
constexpr int U1P = 69;     // u1 column pitch
constexpr int U2P = 77;     // u2 column pitch
constexpr int HW  = 1024 * 1024;
constexpr int NST = (XR * 24 + TB - 1) / TB;   // 9 stage items/thread

__device__ constexpr float K13f[13] = {
    1.f/256, 4.f/256, 10.f/256, 20.f/256, 31.f/256, 40.f/256, 44.f/256,
    40.f/256, 31.f/256, 20.f/256, 10.f/256, 4.f/256, 1.f/256};
__device__ constexpr float K29f[29] = {
    1.f/4096,   4.f/4096,  10.f/4096,  20.f/4096,  35.f/4096,  56.f/4096,
    84.f/4096, 120.f/4096, 161.f/4096, 204.f/4096, 246.f/4096, 284.f/4096,
    315.f/4096, 336.f/4096, 344.f/4096, 336.f/4096, 315.f/4096, 284.f/4096,
    246.f/4096, 204.f/4096, 161.f/4096, 120.f/4096,  84.f/4096,  56.f/4096,
    35.f/4096,  20.f/4096,  10.f/4096,   4.f/4096,   1.f/4096};

__device__ __forceinline__ int refl(int i) {
    return i < 0 ? -i : (i >= 1024 ? 2046 - i : i);
}
__device__ __forceinline__ uint32_t b32(h2v v) { return __builtin_bit_cast(uint32_t, v); }
__device__ __forceinline__ h2v hb(uint32_t v)  { return __builtin_bit_cast(h2v, v); }
__device__ __forceinline__ uint32_t pkrtz(float a, float b) {
    return __builtin_bit_cast(uint32_t, __builtin_amdgcn_cvt_pkrtz(a, b));
}
__device__ __forceinline__ h2v algn(h2v hi, h2v lo) {
    return hb(__builtin_amdgcn_alignbit(b32(hi), b32(lo), 16));
}
__device__ __forceinline__ h2v hsplat(float f) {
    const _Float16 h = (_Float16)f;
    return h2v{h, h};
}
__device__ __forceinline__ f4v tof4(h2v a, h2v b) {
    return f4v{(float)a[0], (float)a[1], (float)b[0], (float)b[1]};
}

// ---- stage helpers ----
__device__ __forceinline__ f4v stage_load(const float* __restrict__ xp,
                                          int e, int bx, int by, bool xedge) {
    const int r = e / 24, m = e - r * 24;
    const int gr = refl(by - VH + r);
    const int gc0 = bx - 16 + 4 * m;
    f4v v;
    if (!xedge || (gc0 >= 0 && gc0 <= 1020)) {
        v = *(const f4v*)(xp + (size_t)gr * 1024 + gc0);
    } else {
#pragma unroll
        for (int q = 0; q < 4; ++q) v[q] = xp[(size_t)gr * 1024 + refl(gc0 + q)];
    }
    return v;
}
__device__ __forceinline__ void stage_store(uint2* __restrict__ xsw, int e, f4v v) {
    const int r = e / 24, m = e - r * 24;
    xsw[m * XCP + r] = uint2{pkrtz(v[0], v[1]), pkrtz(v[2], v[3])};
}

// ---- passA: pk-f16 horizontal cascade; u1/u2 col-major; u3 in-place over xs ----
__device__ __forceinline__ void passA(uint2* __restrict__ xsw,
                                      uint2* __restrict__ u1b,
                                      uint2* __restrict__ u2b, int tid) {
    const h2v W0 = hsplat(0.0625f), W1 = hsplat(0.25f), W2 = hsplat(0.375f);
    for (int t = tid; t < XR * 4; t += TB) {
        const int gi = t & 3;
        const int rp = t >> 2;
        const uint2* base = xsw + (4 * gi) * XCP + rp;
        h2v H[24];
#pragma unroll
        for (int j = 0; j < 12; ++j) {
            const uint2 w = base[j * XCP];
            H[2*j]   = hb(w.x);
            H[2*j+1] = hb(w.y);
        }
        // h1 (d=1)
        {
            h2v roll = algn(H[2], H[1]);
#pragma unroll
            for (int p = 1; p <= 20; ++p) {
                const h2v a1 = roll;
                const h2v a3 = algn(H[p+2], H[p+1]);
                roll = a3;
                H[p] = W0 * (H[p] + H[p+2]) + W1 * (a1 + a3) + W2 * H[p+1];
            }
        }
        if (rp >= 12 && rp < 80) {
            uint2* d = u1b + (4 * gi) * U1P + (rp - 12);
#pragma unroll
            for (int j = 0; j < 4; ++j)
                d[j * U1P] = uint2{b32(H[7 + 2*j]), b32(H[8 + 2*j])};
        }
        // h2 (d=2)
#pragma unroll
        for (int p = 1; p <= 16; ++p)
            H[p] = W0 * (H[p] + H[p+4]) + W1 * (H[p+1] + H[p+3]) + W2 * H[p+2];
        if (rp >= 8 && rp < 84) {
            uint2* d = u2b + (4 * gi) * U2P + (rp - 8);
#pragma unroll
            for (int j = 0; j < 4; ++j)
                d[j * U2P] = uint2{b32(H[5 + 2*j]), b32(H[6 + 2*j])};
        }
        // h3 (d=4)
#pragma unroll
        for (int p = 1; p <= 8; ++p)
            H[p] = W0 * (H[p] + H[p+8]) + W1 * (H[p+2] + H[p+6]) + W2 * H[p+4];
        {
            uint2* d = xsw + (4 * gi) * XCP + rp;
#pragma unroll
            for (int j = 0; j < 4; ++j)
                d[j * XCP] = uint2{b32(H[1 + 2*j]), b32(H[2 + 2*j])};
        }
    }
}

// ---- passB: pk-f16 vertical convs; thread = (f4-col, 4-row strip) ----
__device__ __forceinline__ void passB(const uint2* __restrict__ xsw,
                                      const uint2* __restrict__ u1b,
                                      const uint2* __restrict__ u2b,
                                      int tid, int bx, int by,
                                      const float* __restrict__ xp,
                                      float* __restrict__ op) {
    const h2v W0 = hsplat(0.0625f), W1 = hsplat(0.25f), W2 = hsplat(0.375f);
    const int fc = tid & 15;
    const int r0 = (tid >> 4) * 4;
    const size_t gbase = (size_t)(by + r0) * 1024 + bx + 4 * fc;

    f4v xc[4];
#pragma unroll
    for (int j = 0; j < 4; ++j)
        xc[j] = *(const f4v*)(xp + gbase + (size_t)j * 1024);

    // c1 = V1 u1 (5-tap)
    f4v c1f[4];
    {
        const uint2* b1 = u1b + fc * U1P + r0;
        h2v ua[8], ub[8];
#pragma unroll
        for (int i = 0; i < 8; ++i) {
            const uint2 w = b1[i];
            ua[i] = hb(w.x);
            ub[i] = hb(w.y);
        }
#pragma unroll
        for (int j = 0; j < 4; ++j) {
            const h2v s0 = W0 * (ua[j] + ua[j+4]) + W1 * (ua[j+1] + ua[j+3]) + W2 * ua[j+2];
            const h2v s1 = W0 * (ub[j] + ub[j+4]) + W1 * (ub[j+1] + ub[j+3]) + W2 * ub[j+2];
            c1f[j] = tof4(s0, s1);
        }
    }
#pragma unroll
    for (int j = 0; j < 4; ++j)
        __builtin_nontemporal_store(xc[j] - c1f[j],
            (f4v*)(op + 0 * HW + gbase + (size_t)j * 1024));

    // c2 = V2 u2 (13-tap), dual even/odd accumulators
    f4v c2f[4];
    {
        const uint2* b2 = u2b + fc * U2P + r0;
        h2v A[4][2] = {}, B[4][2] = {};
#pragma unroll
        for (int i = 0; i < 16; ++i) {
            const uint2 w = b2[i];
            const h2v v0 = hb(w.x), v1 = hb(w.y);
#pragma unroll
            for (int j = 0; j < 4; ++j) {
                const int m = i - j;
                if (m >= 0 && m <= 12) {
                    const h2v k = hsplat(K13f[m]);
                    if (i & 1) { B[j][0] += k * v0; B[j][1] += k * v1; }
                    else       { A[j][0] += k * v0; A[j][1] += k * v1; }
                }
            }
        }
#pragma unroll
        for (int j = 0; j < 4; ++j)
            c2f[j] = tof4(A[j][0] + B[j][0], A[j][1] + B[j][1]);
    }
#pragma unroll
    for (int j = 0; j < 4; ++j)
        __builtin_nontemporal_store(c1f[j] - c2f[j],
            (f4v*)(op + 1 * HW + gbase + (size_t)j * 1024));

    // c3 = V3 u3 (29-tap, u3 in xs cols 0..15), dual accumulators
    f4v c3f[4];
    {
        const uint2* b3 = xsw + fc * XCP + r0;
        h2v A[4][2] = {}, B[4][2] = {};
#pragma unroll
        for (int i = 0; i < 32; ++i) {
            const uint2 w = b3[i];
            const h2v v0 = hb(w.x), v1 = hb(w.y);
#pragma unroll
            for (int j = 0; j < 4; ++j) {
                const int m = i - j;
                if (m >= 0 && m <= 28) {
                    const h2v k = hsplat(K29f[m]);
                    if (i & 1) { B[j][0] += k * v0; B[j][1] += k * v1; }
                    else       { A[j][0] += k * v0; A[j][1] += k * v1; }
                }
            }
        }
#pragma unroll
        for (int j = 0; j < 4; ++j)
            c3f[j] = tof4(A[j][0] + B[j][0], A[j][1] + B[j][1]);
    }
#pragma unroll
    for (int j = 0; j < 4; ++j) {
        __builtin_nontemporal_store(c2f[j] - c3f[j],
            (f4v*)(op + 2 * HW + gbase + (size_t)j * 1024));
        __builtin_nontemporal_store(c3f[j],
            (f4v*)(op + 3 * HW + gbase + (size_t)j * 1024));
    }
}

__global__ __launch_bounds__(TB)
void uwt3_kernel(const float* __restrict__ x, float* __restrict__ out)
{
    __shared__ uint2 xsw[24 * XCP];
    __shared__ uint2 u1b[16 * U1P];
    __shared__ uint2 u2b[16 * U2P];

    const int tid = threadIdx.x;

    // bijective XCD chunk swizzle over 2048 pair-blocks (2048 % 8 == 0)
    const int flat = blockIdx.x;                 // 0..2047
    const int swz  = (flat & 7) * 256 + (flat >> 3);
    const int tA = swz * 2;                      // even tile id
    const int tB = tA + 1;                       // horizontally adjacent

    const int bxiA = tA & 15, byi = (tA >> 4) & 15, bz = tA >> 8;
    const int bxiB = tB & 15;
    const int bxA = bxiA * 64, bxB = bxiB * 64;
    const int by  = byi * 64;
    const bool edgeA = (bxiA == 0);              // even -> never 15
    const bool edgeB = (bxiB == 15);             // odd  -> never 0

    const float* xp = x + (size_t)bz * HW;
    float* op = out + (size_t)bz * 4 * HW;

    // ---- stage A (direct) ----
#pragma unroll
    for (int it = 0; it < NST; ++it) {
        const int e = tid + it * TB;
        if (e < XR * 24) stage_store(xsw, e, stage_load(xp, e, bxA, by, edgeA));
    }
    __syncthreads();

    // ---- prefetch B stage into registers (in flight across A's compute) ----
    f4v pf[NST];
#pragma unroll
    for (int it = 0; it < NST; ++it) {
        int e = tid + it * TB;
        if (e >= XR * 24) e = XR * 24 - 1;       // clamp (harmless dup)
        pf[it] = stage_load(xp, e, bxB, by, edgeB);
    }

    passA(xsw, u1b, u2b, tid);
    __syncthreads();
    passB(xsw, u1b, u2b, tid, bxA, by, xp, op);
    __syncthreads();                             // all A LDS reads complete

    // ---- stage B from prefetched registers ----
#pragma unroll
    for (int it = 0; it < NST; ++it) {
        const int e = tid + it * TB;
        if (e < XR * 24) stage_store(xsw, e, pf[it]);
    }
    __syncthreads();

    passA(xsw, u1b, u2b, tid);
    __syncthreads();
    passB(xsw, u1b, u2b, tid, bxB, by, xp, op);
}

extern "C" void kernel_launch(void* const* d_in, const int* in_sizes, int n_in,
                              void* d_out, int out_size, void* d_ws, size_t ws_size,
                              hipStream_t stream)
{
    const float* x = (const float*)d_in[0];
    float* out = (float*)d_out;
    uwt3_kernel<<<dim3(2048), dim3(TB), 0, stream>>>(x, out);
}

// Round 17
// 63.284 us; speedup vs baseline: 1.0682x; 1.0682x over previous
//
#include <hip/hip_runtime.h>
#include <stdint.h>

// Fused 3-level B3-spline UWT, fp32 in/out. x:(16,1024,1024)->out:(16,4,1024,1024).
// R15 pk-f16 structure, widened to a 128x64 output tile (TB=512):
//  - xs frame 92 rows x 160 cols f16 col-major (40 uint2-cols, pitch 93)
//  - horizontal halo amortized over 2 tiles (1.25x vs 1.5x read amp),
//    passA cascade work -17% per output, barriers per output halved
//  - u1/u2: 32 uint2-cols (pitch 69/77); u3 in-place over xs cols 0..31
//  - passB: fc = tid&31 (32 f4-cols), 16 strips x 4 rows; 512B wave stores
// 65.6 KB LDS -> 2 blocks/CU x 8 waves = 16 waves/CU (same as R15).

typedef float     f4v __attribute__((ext_vector_type(4)));
typedef _Float16  h2v __attribute__((ext_vector_type(2)));

constexpr int TB  = 512;
constexpr int VH  = 14;     // vertical halo (2+4+8)
constexpr int XR  = 92;     // xs rows
constexpr int FC4 = 40;     // frame f4-groups per row (160 cols)
constexpr int XCP = 93;     // xs column pitch (uint2 slots), odd
constexpr int U1P = 69;     // u1 column pitch
constexpr int U2P = 77;     // u2 column pitch
constexpr int NGI = 8;      // passA 16-col groups per row
constexpr int HW  = 1024 * 1024;

__device__ constexpr float K13f[13] = {
    1.f/256, 4.f/256, 10.f/256, 20.f/256, 31.f/256, 40.f/256, 44.f/256,
    40.f/256, 31.f/256, 20.f/256, 10.f/256, 4.f/256, 1.f/256};
__device__ constexpr float K29f[29] = {
    1.f/4096,   4.f/4096,  10.f/4096,  20.f/4096,  35.f/4096,  56.f/4096,
    84.f/4096, 120.f/4096, 161.f/4096, 204.f/4096, 246.f/4096, 284.f/4096,
    315.f/4096, 336.f/4096, 344.f/4096, 336.f/4096, 315.f/4096, 284.f/4096,
    246.f/4096, 204.f/4096, 161.f/4096, 120.f/4096,  84.f/4096,  56.f/4096,
    35.f/4096,  20.f/4096,  10.f/4096,   4.f/4096,   1.f/4096};

__device__ __forceinline__ int refl(int i) {
    return i < 0 ? -i : (i >= 1024 ? 2046 - i : i);
}
__device__ __forceinline__ uint32_t b32(h2v v) { return __builtin_bit_cast(uint32_t, v); }
__device__ __forceinline__ h2v hb(uint32_t v)  { return __builtin_bit_cast(h2v, v); }
__device__ __forceinline__ uint32_t pkrtz(float a, float b) {
    return __builtin_bit_cast(uint32_t, __builtin_amdgcn_cvt_pkrtz(a, b));
}
__device__ __forceinline__ h2v algn(h2v hi, h2v lo) {
    return hb(__builtin_amdgcn_alignbit(b32(hi), b32(lo), 16));
}
__device__ __forceinline__ h2v hsplat(float f) {
    const _Float16 h = (_Float16)f;
    return h2v{h, h};
}
__device__ __forceinline__ f4v tof4(h2v a, h2v b) {
    return f4v{(float)a[0], (float)a[1], (float)b[0], (float)b[1]};
}

__global__ __launch_bounds__(TB)
void uwt3_kernel(const float* __restrict__ x, float* __restrict__ out)
{
    __shared__ uint2 xsw[FC4 * XCP];   // 29760 B (stage; cols 0..31 become u3)
    __shared__ uint2 u1b[32 * U1P];    // 17664 B
    __shared__ uint2 u2b[32 * U2P];    // 19712 B   total 67136 B

    const int tid = threadIdx.x;

    // bijective XCD chunk swizzle over 2048 blocks (2048 % 8 == 0)
    const int flat = blockIdx.x;                 // 0..2047
    const int swz  = (flat & 7) * 256 + (flat >> 3);
    const int pxi = swz & 7;                     // x-pair index 0..7
    const int byi = (swz >> 3) & 15;
    const int bz  = swz >> 7;
    const int bx = pxi * 128;
    const int by = byi * 64;
    const bool xedge = (pxi == 0) || (pxi == 7);

    const float* xp = x + (size_t)bz * HW;
    float* op = out + (size_t)bz * 4 * HW;

    // ---- stage: x rows [by-14,by+78), cols [bx-16,bx+144) -> f16 col-major ----
    for (int e = tid; e < XR * FC4; e += TB) {
        const int r = e / FC4, m = e - r * FC4;
        const int gr = refl(by - VH + r);
        const int gc0 = bx - 16 + 4 * m;
        f4v v;
        if (!xedge || (gc0 >= 0 && gc0 <= 1020)) {
            v = *(const f4v*)(xp + (size_t)gr * 1024 + gc0);
        } else {
#pragma unroll
            for (int q = 0; q < 4; ++q) v[q] = xp[(size_t)gr * 1024 + refl(gc0 + q)];
        }
        xsw[m * XCP + r] = uint2{pkrtz(v[0], v[1]), pkrtz(v[2], v[3])};
    }
    __syncthreads();

    const h2v W0 = hsplat(0.0625f), W1 = hsplat(0.25f), W2 = hsplat(0.375f);

    // ---- passA: pk-f16 horizontal cascade; u1/u2 col-major; u3 in-place ----
    // item = (row rp, group gi in [0,8)); a row's 8 items are 8 consecutive
    // lanes of one wave -> lockstep reads-before-writes makes in-place u3 safe.
    for (int t = tid; t < XR * NGI; t += TB) {
        const int gi = t & 7;
        const int rp = t >> 3;
        const uint2* base = xsw + (4 * gi) * XCP + rp;
        h2v H[24];                       // H[p] = (F[2p], F[2p+1])
#pragma unroll
        for (int j = 0; j < 12; ++j) {
            const uint2 w = base[j * XCP];
            H[2*j]   = hb(w.x);
            H[2*j+1] = hb(w.y);
        }
        // h1 (d=1): pairs 1..20
        {
            h2v roll = algn(H[2], H[1]);
#pragma unroll
            for (int p = 1; p <= 20; ++p) {
                const h2v a1 = roll;
                const h2v a3 = algn(H[p+2], H[p+1]);
                roll = a3;
                H[p] = W0 * (H[p] + H[p+2]) + W1 * (a1 + a3) + W2 * H[p+1];
            }
        }
        if (rp >= 12 && rp < 80) {        // u1 = h1 center = pairs 7..14
            uint2* d = u1b + (4 * gi) * U1P + (rp - 12);
#pragma unroll
            for (int j = 0; j < 4; ++j)
                d[j * U1P] = uint2{b32(H[7 + 2*j]), b32(H[8 + 2*j])};
        }
        // h2 (d=2): pairs 1..16
#pragma unroll
        for (int p = 1; p <= 16; ++p)
            H[p] = W0 * (H[p] + H[p+4]) + W1 * (H[p+1] + H[p+3]) + W2 * H[p+2];
        if (rp >= 8 && rp < 84) {         // u2 = h2 center = pairs 5..12
            uint2* d = u2b + (4 * gi) * U2P + (rp - 8);
#pragma unroll
            for (int j = 0; j < 4; ++j)
                d[j * U2P] = uint2{b32(H[5 + 2*j]), b32(H[6 + 2*j])};
        }
        // h3 (d=4): pairs 1..8
#pragma unroll
        for (int p = 1; p <= 8; ++p)
            H[p] = W0 * (H[p] + H[p+8]) + W1 * (H[p+2] + H[p+6]) + W2 * H[p+4];
        {                                 // u3 = h3 center -> xs cols 4gi..4gi+3
            uint2* d = xsw + (4 * gi) * XCP + rp;
#pragma unroll
            for (int j = 0; j < 4; ++j)
                d[j * XCP] = uint2{b32(H[1 + 2*j]), b32(H[2 + 2*j])};
        }
    }
    __syncthreads();

    // ---- passB: pk-f16 vertical convs; thread = (f4-col of 32, 4-row strip) ----
    const int fc = tid & 31;
    const int r0 = (tid >> 5) * 4;
    const size_t gbase = (size_t)(by + r0) * 1024 + bx + 4 * fc;

    // x re-read issued early (L2/L3-hot)
    f4v xc[4];
#pragma unroll
    for (int j = 0; j < 4; ++j)
        xc[j] = *(const f4v*)(xp + gbase + (size_t)j * 1024);

    // c1 = V1 u1 (5-tap)
    f4v c1f[4];
    {
        const uint2* b1 = u1b + fc * U1P + r0;
        h2v ua[8], ub[8];
#pragma unroll
        for (int i = 0; i < 8; ++i) {
            const uint2 w = b1[i];
            ua[i] = hb(w.x);
            ub[i] = hb(w.y);
        }
#pragma unroll
        for (int j = 0; j < 4; ++j) {
            const h2v s0 = W0 * (ua[j] + ua[j+4]) + W1 * (ua[j+1] + ua[j+3]) + W2 * ua[j+2];
            const h2v s1 = W0 * (ub[j] + ub[j+4]) + W1 * (ub[j+1] + ub[j+3]) + W2 * ub[j+2];
            c1f[j] = tof4(s0, s1);
        }
    }
#pragma unroll
    for (int j = 0; j < 4; ++j)
        __builtin_nontemporal_store(xc[j] - c1f[j],
            (f4v*)(op + 0 * HW + gbase + (size_t)j * 1024));

    // c2 = V2 u2 (13-tap), dual even/odd accumulators
    f4v c2f[4];
    {
        const uint2* b2 = u2b + fc * U2P + r0;
        h2v A[4][2] = {}, B[4][2] = {};
#pragma unroll
        for (int i = 0; i < 16; ++i) {
            const uint2 w = b2[i];
            const h2v v0 = hb(w.x), v1 = hb(w.y);
#pragma unroll
            for (int j = 0; j < 4; ++j) {
                const int m = i - j;
                if (m >= 0 && m <= 12) {
                    const h2v k = hsplat(K13f[m]);
                    if (i & 1) { B[j][0] += k * v0; B[j][1] += k * v1; }
                    else       { A[j][0] += k * v0; A[j][1] += k * v1; }
                }
            }
        }
#pragma unroll
        for (int j = 0; j < 4; ++j)
            c2f[j] = tof4(A[j][0] + B[j][0], A[j][1] + B[j][1]);
    }
#pragma unroll
    for (int j = 0; j < 4; ++j)
        __builtin_nontemporal_store(c1f[j] - c2f[j],
            (f4v*)(op + 1 * HW + gbase + (size_t)j * 1024));

    // c3 = V3 u3 (29-tap, u3 in xs cols 0..31), dual accumulators
    f4v c3f[4];
    {
        const uint2* b3 = xsw + fc * XCP + r0;
        h2v A[4][2] = {}, B[4][2] = {};
#pragma unroll
        for (int i = 0; i < 32; ++i) {
            const uint2 w = b3[i];
            const h2v v0 = hb(w.x), v1 = hb(w.y);
#pragma unroll
            for (int j = 0; j < 4; ++j) {
                const int m = i - j;
                if (m >= 0 && m <= 28) {
                    const h2v k = hsplat(K29f[m]);
                    if (i & 1) { B[j][0] += k * v0; B[j][1] += k * v1; }
                    else       { A[j][0] += k * v0; A[j][1] += k * v1; }
                }
            }
        }
#pragma unroll
        for (int j = 0; j < 4; ++j)
            c3f[j] = tof4(A[j][0] + B[j][0], A[j][1] + B[j][1]);
    }
#pragma unroll
    for (int j = 0; j < 4; ++j) {
        __builtin_nontemporal_store(c2f[j] - c3f[j],
            (f4v*)(op + 2 * HW + gbase + (size_t)j * 1024));
        __builtin_nontemporal_store(c3f[j],
            (f4v*)(op + 3 * HW + gbase + (size_t)j * 1024));
    }
}

extern "C" void kernel_launch(void* const* d_in, const int* in_sizes, int n_in,
                              void* d_out, int out_size, void* d_ws, size_t ws_size,
                              hipStream_t stream)
{
    const float* x = (const float*)d_in[0];
    float* out = (float*)d_out;
    uwt3_kernel<<<dim3(2048), dim3(TB), 0, stream>>>(x, out);
}